// Round 4
// baseline (256.467 us; speedup 1.0000x reference)
//
#include <hip/hip_runtime.h>

// EGNNLayer — MI355X (gfx950)
// B=16 N=64 P=192 NP=256 H=64 E=32 M=64 O=64 T=256
// dtypes: fp32 in/out. Masks all-True -> diag-only mask, n_msg=255.
//
// R19: occupancy tier fix. R18 landed at 80 arch + 64 AGPR = 144 regs ->
//   3 waves/SIMD, 1.33 grid rounds; R15/R18 scaling shows wall ~ 1/waves.
//   Two-pass j-split (each pass: 128 j, wave owns 32 j) halves msgacc to
//   32 regs -> total ~110 <= 128 -> 4 waves/SIMD, grid 1024 = one clean
//   4-block/CU round. A1 split to E[64][40]+G[256][40] f16 (LDS ~36KB),
//   HJB + base stored f16 (halves the 256KB/block L2 stream + transients).
//   Total MFMA unchanged; weights re-streamed once more per block (cheap).

typedef _Float16 f16;
typedef f16 f16x8 __attribute__((ext_vector_type(8)));
typedef f16 f16x4 __attribute__((ext_vector_type(4)));
typedef float f32x4 __attribute__((ext_vector_type(4)));
typedef unsigned u32x4 __attribute__((ext_vector_type(4)));
typedef unsigned u32x2 __attribute__((ext_vector_type(2)));
#define MFMA16(a, b, c) __builtin_amdgcn_mfma_f32_16x16x32_f16(a, b, c, 0, 0, 0)

#define B_ 16
#define N_ 64
#define P_ 192
#define NP_ 256
#define H_ 64
#define T_ 256

// ---- ws layout (float offsets) ----
#define OFF_HIA    0         // (B*N, 256) fp32
#define OFF_HJB    262144    // (B, 256j, 256c) f16  [R19: f16]
#define OFF_B1T    1379328   // f16: W1E [256c][32k] then W1G [256c][32k]
#define OFF_W2T    1387520   // f16 [64m][256c] = Wm2^T
#define OFF_WT1H   1395712   // f16 [256c][64m] = Wt1^T
#define OFF_W1AT   1403904   // f16 [256c][64k] = Wm1 rows 0..63 ^T
#define OFF_W1BT   1412096   // f16 [256c][64k] = Wm1 rows 64..127 ^T

// output layout (flat fp32)
#define OUT_UPDQ 0
#define OUT_UPDX 4096
#define OUT_UPDT 7168
#define OUT_O    21504

__device__ __forceinline__ void qrot(float qw, float qx, float qy, float qz,
                                     float vx, float vy, float vz,
                                     float& ox, float& oy, float& oz) {
    float tx = 2.f * (qy * vz - qz * vy);
    float ty = 2.f * (qz * vx - qx * vz);
    float tz = 2.f * (qx * vy - qy * vx);
    ox = vx + qw * tx + (qy * tz - qz * ty);
    oy = vy + qw * ty + (qz * tx - qx * tz);
    oz = vz + qw * tz + (qx * ty - qy * tx);
}

__device__ __forceinline__ unsigned pk2(float a, float b) {
    return __builtin_bit_cast(unsigned, __builtin_amdgcn_cvt_pkrtz(a, b));
}

struct Wts {
    const float *Wm1,*bm1,*Wm2,*bm2,*Wf1,*bf1,*Wf2,*bf2,*Wt1,*bt1,*Wt2,*bt2,
                *Wq1,*bq1,*Wq2,*bq2,*Wo1,*bo1,*Wo2,*bo2;
};

// grid 320 x 256: build W1E/W1G, W2T, WT1H, W1AT, W1BT (f16) in ws
__global__ __launch_bounds__(256) void k_prep(const float* __restrict__ Wm1,
                                              const float* __restrict__ Wm2,
                                              const float* __restrict__ Wt1,
                                              float* __restrict__ ws) {
    int t = blockIdx.x * 256 + threadIdx.x;  // < 81920
    if (t < 8192) {
        // W1E [256c][32k]: edge rows 128..159 of Wm1
        f16* W1E = (f16*)(ws + OFF_B1T);
        int c = t >> 5, k = t & 31;
        W1E[t] = (f16)Wm1[(128 + k) * 256 + c];
    } else if (t < 16384) {
        // W1G [256c][32k]: geo rows 160..168, rest zero
        f16* W1G = (f16*)(ws + OFF_B1T) + 8192;
        int u = t - 8192;
        int c = u >> 5, k = u & 31;
        float v = (k < 9) ? Wm1[(160 + k) * 256 + c] : 0.f;
        W1G[u] = (f16)v;
    } else if (t < 32768) {
        f16* W2T = (f16*)(ws + OFF_W2T);
        int u = t - 16384;
        int m = u >> 8, c = u & 255;
        W2T[u] = (f16)Wm2[c * 64 + m];
    } else if (t < 49152) {
        f16* W1H = (f16*)(ws + OFF_WT1H);
        int u = t - 32768;
        int c = u >> 6, m = u & 63;
        W1H[u] = (f16)Wt1[m * 256 + c];
    } else if (t < 65536) {
        f16* W1A = (f16*)(ws + OFF_W1AT);
        int u = t - 49152;
        int c = u >> 6, k = u & 63;
        W1A[u] = (f16)Wm1[k * 256 + c];
    } else {
        f16* W1B = (f16*)(ws + OFF_W1BT);
        int u = t - 65536;
        int c = u >> 6, k = u & 63;
        W1B[u] = (f16)Wm1[(64 + k) * 256 + c];
    }
}

// grid (4 ct, 16 b) x 256 — MFMA h-dots.  HJB stored transposed [j][c] f16.
__global__ __launch_bounds__(256) void k_dots(const float* __restrict__ pep_h,
                                              const float* __restrict__ poc_h,
                                              float* __restrict__ ws) {
    const int ct = blockIdx.x;
    const int b = blockIdx.y;
    const int tid = threadIdx.x;
    const int lane = tid & 63;
    const int wv = tid >> 6;
    const int lm = lane & 15;
    const int lq = lane >> 4;

    __shared__ __align__(16) f16 hL[256 * 64];

    {
        const float4* p4 = (const float4*)(pep_h + (size_t)b * 4096);
        #pragma unroll
        for (int it = 0; it < 4; it++) {
            int idx = it * 256 + tid;
            float4 v = p4[idx];
            f16x4 h = {(f16)v.x, (f16)v.y, (f16)v.z, (f16)v.w};
            *(f16x4*)&hL[idx * 4] = h;
        }
        const float4* q4 = (const float4*)(poc_h + (size_t)b * 12288);
        #pragma unroll
        for (int it = 0; it < 12; it++) {
            int idx = it * 256 + tid;
            float4 v = q4[idx];
            f16x4 h = {(f16)v.x, (f16)v.y, (f16)v.z, (f16)v.w};
            *(f16x4*)&hL[4096 + idx * 4] = h;
        }
    }
    __syncthreads();

    const f16* W1AT = (const f16*)(ws + OFF_W1AT);
    const f16* W1BT = (const f16*)(ws + OFF_W1BT);

    f32x4 acc[4][4];
    #pragma unroll
    for (int mt = 0; mt < 4; mt++)
        #pragma unroll
        for (int nt = 0; nt < 4; nt++) acc[mt][nt] = (f32x4){0.f, 0.f, 0.f, 0.f};

    f16x8 af[4][2], bf[4][2];
    #pragma unroll
    for (int mt = 0; mt < 4; mt++) {
        const int c = ct * 64 + mt * 16 + lm;
        af[mt][0] = *(const f16x8*)&W1BT[c * 64 + lq * 8];
        af[mt][1] = *(const f16x8*)&W1BT[c * 64 + 32 + lq * 8];
    }
    #pragma unroll
    for (int nt = 0; nt < 4; nt++) {
        const int jj = wv * 64 + nt * 16 + lm;
        bf[nt][0] = *(const f16x8*)&hL[jj * 64 + lq * 8];
        bf[nt][1] = *(const f16x8*)&hL[jj * 64 + 32 + lq * 8];
    }
    #pragma unroll
    for (int mt = 0; mt < 4; mt++)
        #pragma unroll
        for (int nt = 0; nt < 4; nt++) {
            acc[mt][nt] = MFMA16(af[mt][0], bf[nt][0], acc[mt][nt]);
            acc[mt][nt] = MFMA16(af[mt][1], bf[nt][1], acc[mt][nt]);
        }
    // D[c][j] tile -> store transposed [j][c] as f16 (pk2 pairs).
    f16* HJ = (f16*)(ws + OFF_HJB) + (size_t)b * 65536;
    #pragma unroll
    for (int mt = 0; mt < 4; mt++)
        #pragma unroll
        for (int nt = 0; nt < 4; nt++) {
            u32x2 pkd = { pk2(acc[mt][nt][0], acc[mt][nt][1]),
                          pk2(acc[mt][nt][2], acc[mt][nt][3]) };
            *(u32x2*)&HJ[(size_t)(wv * 64 + nt * 16 + lm) * 256 +
                         ct * 64 + mt * 16 + lq * 4] = pkd;
        }

    f32x4 ha[4];
    #pragma unroll
    for (int nt = 0; nt < 4; nt++) ha[nt] = (f32x4){0.f, 0.f, 0.f, 0.f};
    f16x8 a0 = *(const f16x8*)&hL[(wv * 16 + lm) * 64 + lq * 8];
    f16x8 a1 = *(const f16x8*)&hL[(wv * 16 + lm) * 64 + 32 + lq * 8];
    #pragma unroll
    for (int nt = 0; nt < 4; nt++) {
        const int c = ct * 64 + nt * 16 + lm;
        f16x8 b0 = *(const f16x8*)&W1AT[c * 64 + lq * 8];
        f16x8 b1 = *(const f16x8*)&W1AT[c * 64 + 32 + lq * 8];
        ha[nt] = MFMA16(a0, b0, ha[nt]);
        ha[nt] = MFMA16(a1, b1, ha[nt]);
    }
    #pragma unroll
    for (int nt = 0; nt < 4; nt++)
        #pragma unroll
        for (int r = 0; r < 4; r++)
            ws[OFF_HIA + (size_t)(b * 64 + wv * 16 + lq * 4 + r) * 256 +
               ct * 64 + nt * 16 + lm] = ha[nt][r];
}

// grid 1024 x 256.  XCD swizzle: b = blk&15, i = blk>>4.
// Two passes over j (128 each); wave owns 32 j per pass. msgacc 32 regs.
__global__ __launch_bounds__(256, 2) void k_edge(const float* __restrict__ pep_q,
                                                 const float* __restrict__ pep_x,
                                                 const float* __restrict__ pep_t,
                                                 const float* __restrict__ pep_h,
                                                 const float* __restrict__ ef,
                                                 const float* __restrict__ poc_q,
                                                 const float* __restrict__ poc_x,
                                                 Wts W, float* __restrict__ ws,
                                                 float* __restrict__ out) {
    const int b = blockIdx.x & 15;
    const int i = blockIdx.x >> 4;
    const int node = b * 64 + i;
    const int tid = threadIdx.x;
    const int j = tid;
    const int lane = tid & 63;
    const int wv = tid >> 6;
    const int lm = lane & 15;
    const int lq = lane >> 4;
    const float cfac = 1.f / 255.f;  // n_msg = 63 pep + 192 pocket

    // E [64][40] f16 (edge feats, rows j<64) + G [256][40] f16 (geo, 9 used,
    // cols 9..31 zero). 80B row stride: 16B-aligned, ~2-way banks. Dead after
    // the pass loop; tail FB overlays POOL.
    __shared__ __align__(16) unsigned char POOL[25600];
    f16* const E_ = (f16*)POOL;                // [64][40]
    f16* const G_ = (f16*)(POOL + 5120);       // [256][40]
    __shared__ float DXB[768];                 // [256 j][3]
    __shared__ f16 base_h[256];
    __shared__ float bt1s[256], wt2sT[768], bm2s[64];
    __shared__ float msump2[8][64];            // [pass*4+wv][m]
    __shared__ float rotp[4][3];
    __shared__ float MS_s[64], MSC_s[64], ROT_s[3], DQ_s[4], DT_s[14];

    // ---------------- phase 0: staging + per-j geometry ----------------
    base_h[tid] = (f16)(ws[OFF_HIA + (size_t)node * T_ + tid] + W.bm1[tid]);
    bt1s[tid] = W.bt1[tid];
    wt2sT[tid]       = W.Wt2[tid * 3 + 0];   // Wt2^T: [3][256]
    wt2sT[256 + tid] = W.Wt2[tid * 3 + 1];
    wt2sT[512 + tid] = W.Wt2[tid * 3 + 2];
    if (tid < 64) bm2s[tid] = W.bm2[tid];

    const bool pep = (j < N_);
    {
        const float4 qi4 = *reinterpret_cast<const float4*>(pep_q + (b * N_ + i) * 4);
        const float qiw = qi4.x, qix = qi4.y, qiy = qi4.z, qiz = qi4.w;
        const float* tip = pep_x + (b * N_ + i) * 3;
        const float tix = tip[0], tiy = tip[1], tiz = tip[2];

        float qjw, qjx, qjy, qjz, xjx, xjy, xjz;
        if (pep) {
            const float4 q4 = *reinterpret_cast<const float4*>(pep_q + (b * N_ + j) * 4);
            qjw = q4.x; qjx = q4.y; qjy = q4.z; qjz = q4.w;
            const float* xp = pep_x + (b * N_ + j) * 3;
            xjx = xp[0]; xjy = xp[1]; xjz = xp[2];
        } else {
            const float4 q4 = *reinterpret_cast<const float4*>(poc_q + (b * P_ + (j - N_)) * 4);
            qjw = q4.x; qjx = q4.y; qjy = q4.z; qjz = q4.w;
            const float* xp = poc_x + (b * P_ + (j - N_)) * 3;
            xjx = xp[0]; xjy = xp[1]; xjz = xp[2];
        }

        const float vw = qjw, vx = -qjx, vy = -qjy, vz = -qjz;
        float tnx, tny, tnz;
        qrot(vw, vx, vy, vz, xjx, xjy, xjz, tnx, tny, tnz);
        float lxx, lxy, lxz;
        qrot(vw, vx, vy, vz, tix, tiy, tiz, lxx, lxy, lxz);
        lxx -= tnx; lxy -= tny; lxz -= tnz;
        float lqw = vw * qiw - vx * qix - vy * qiy - vz * qiz;
        float lqx = vw * qix + vx * qiw + vy * qiz - vz * qiy;
        float lqy = vw * qiy - vx * qiz + vy * qiw + vz * qix;
        float lqz = vw * qiz + vx * qiy - vy * qix + vz * qiw;
        float ddx = tix - xjx, ddy = tiy - xjy, ddz = tiz - xjz;
        float d2 = ddx * ddx + ddy * ddy + ddz * ddz;
        float qd = fabsf(qiw * qjw + qix * qjx + qiy * qjy + qiz * qjz);

        const f16x8 z = {(f16)0,(f16)0,(f16)0,(f16)0,(f16)0,(f16)0,(f16)0,(f16)0};
        if (pep) {
            const float4* ep = reinterpret_cast<const float4*>(
                ef + (size_t)(((b * N_ + i) * N_) + j) * 32);
            f16* erow = &E_[j * 40];
            #pragma unroll
            for (int gr = 0; gr < 4; gr++) {
                float4 v0 = ep[gr * 2], v1 = ep[gr * 2 + 1];
                f16x8 h;
                h[0]=(f16)v0.x; h[1]=(f16)v0.y; h[2]=(f16)v0.z; h[3]=(f16)v0.w;
                h[4]=(f16)v1.x; h[5]=(f16)v1.y; h[6]=(f16)v1.z; h[7]=(f16)v1.w;
                *(f16x8*)(erow + gr * 8) = h;
            }
        }
        f16* grow = &G_[j * 40];
        f16x8 hg;
        hg[0]=(f16)lxx; hg[1]=(f16)lxy; hg[2]=(f16)lxz; hg[3]=(f16)lqw;
        hg[4]=(f16)lqx; hg[5]=(f16)lqy; hg[6]=(f16)lqz; hg[7]=(f16)d2;
        *(f16x8*)(grow) = hg;
        f16x8 h2 = z; h2[0] = (f16)qd;
        *(f16x8*)(grow + 8) = h2;
        *(f16x8*)(grow + 16) = z;
        *(f16x8*)(grow + 24) = z;
    }
    __syncthreads();  // barrier 1

    const f16* W1Eg = (const f16*)(ws + OFF_B1T);
    const f16* W1Gg = W1Eg + 8192;
    const f16* W2Tg = (const f16*)(ws + OFF_W2T);
    const f16* W1Hg = (const f16*)(ws + OFF_WT1H);
    const f16* hjb16 = (const f16*)(ws + OFF_HJB) + (size_t)b * 65536;

    const f16x8 zf = {(f16)0,(f16)0,(f16)0,(f16)0,(f16)0,(f16)0,(f16)0,(f16)0};
    const int s01 = lm + (lq & 1) * 32;   // transpose-shuffle source
    const bool hi32 = (lane >= 32);
    const int iw = i >> 5, itile = (i >> 4) & 1, ilm = i & 15;

    #pragma unroll 1
    for (int pass = 0; pass < 2; ++pass) {
        const int jbase = pass * 128 + wv * 32;
        const bool hasE = (pass == 0) && (wv < 2);

        // msgacc[m-tile u][j-tile mt]: lane m = u*16+lq*4+r, j = jbase+mt*16+lm
        f32x4 msgacc[4][2];
        #pragma unroll
        for (int u = 0; u < 4; u++)
            #pragma unroll
            for (int mt = 0; mt < 2; mt++) msgacc[u][mt] = (f32x4){0.f,0.f,0.f,0.f};

        // ------- phase 1: 8 chunks of 32 c -------
        #pragma unroll 1
        for (int ch = 0; ch < 8; ch++) {
            const int c0 = ch * 32;
            f16x8 g1e0 = zf, g1e1 = zf;
            if (hasE) {
                g1e0 = *(const f16x8*)&W1Eg[(c0 + lm) * 32 + lq * 8];
                g1e1 = *(const f16x8*)&W1Eg[(c0 + 16 + lm) * 32 + lq * 8];
            }
            const f16x8 g1g0 = *(const f16x8*)&W1Gg[(c0 + lm) * 32 + lq * 8];
            const f16x8 g1g1 = *(const f16x8*)&W1Gg[(c0 + 16 + lm) * 32 + lq * 8];
            f16x8 g2[4];
            #pragma unroll
            for (int u = 0; u < 4; u++)
                g2[u] = *(const f16x8*)&W2Tg[(u * 16 + lm) * 256 + c0 + lq * 8];

            #pragma unroll
            for (int mt = 0; mt < 2; mt++) {
                const int jr = jbase + mt * 16 + lm;
                const f16x8 aG = *(const f16x8*)&G_[jr * 40 + lq * 8];
                f16x8 aE = zf;
                if (hasE) aE = *(const f16x8*)&E_[jr * 40 + lq * 8];

                unsigned p00, p01, p10, p11;  // packed relu(T1) tiles nt=0,1
                {
                    f32x4 acc = {0.f,0.f,0.f,0.f};
                    if (hasE) acc = MFMA16(g1e0, aE, acc);
                    acc = MFMA16(g1g0, aG, acc);
                    const f16x4 hv = *(const f16x4*)&hjb16[(size_t)jr * 256 + c0 + lq * 4];
                    const f16x4 bb = *(const f16x4*)&base_h[c0 + lq * 4];
                    float u0 = fmaxf(acc[0] + (float)hv[0] + (float)bb[0], 0.f);
                    float u1 = fmaxf(acc[1] + (float)hv[1] + (float)bb[1], 0.f);
                    float u2 = fmaxf(acc[2] + (float)hv[2] + (float)bb[2], 0.f);
                    float u3 = fmaxf(acc[3] + (float)hv[3] + (float)bb[3], 0.f);
                    p00 = pk2(u0, u1); p01 = pk2(u2, u3);
                }
                {
                    f32x4 acc = {0.f,0.f,0.f,0.f};
                    if (hasE) acc = MFMA16(g1e1, aE, acc);
                    acc = MFMA16(g1g1, aG, acc);
                    const f16x4 hv = *(const f16x4*)&hjb16[(size_t)jr * 256 + c0 + 16 + lq * 4];
                    const f16x4 bb = *(const f16x4*)&base_h[c0 + 16 + lq * 4];
                    float u0 = fmaxf(acc[0] + (float)hv[0] + (float)bb[0], 0.f);
                    float u1 = fmaxf(acc[1] + (float)hv[1] + (float)bb[1], 0.f);
                    float u2 = fmaxf(acc[2] + (float)hv[2] + (float)bb[2], 0.f);
                    float u3 = fmaxf(acc[3] + (float)hv[3] + (float)bb[3], 0.f);
                    p10 = pk2(u0, u1); p11 = pk2(u2, u3);
                }
                // transpose: D[c][j] tiles -> B-frag [k=c][col=j] for GEMM2
                unsigned w0, w1, w2, w3;
                {
                    unsigned t0 = __shfl((int)p00, s01);
                    unsigned t1 = __shfl((int)p10, s01);
                    w0 = hi32 ? t1 : t0;
                    t0 = __shfl((int)p01, s01);
                    t1 = __shfl((int)p11, s01);
                    w1 = hi32 ? t1 : t0;
                    t0 = __shfl((int)p00, s01 + 16);
                    t1 = __shfl((int)p10, s01 + 16);
                    w2 = hi32 ? t1 : t0;
                    t0 = __shfl((int)p01, s01 + 16);
                    t1 = __shfl((int)p11, s01 + 16);
                    w3 = hi32 ? t1 : t0;
                }
                const f16x8 bfr = __builtin_bit_cast(f16x8, (u32x4){w0, w1, w2, w3});
                #pragma unroll
                for (int u = 0; u < 4; u++)
                    msgacc[u][mt] = MFMA16(g2[u], bfr, msgacc[u][mt]);
            }
        }

        // -------- phase 2: bias + diag mask + partial msg_sum --------
        #pragma unroll
        for (int mt = 0; mt < 2; mt++) {
            const float dm = (pass == 0 && wv == iw && mt == itile && lm == ilm)
                                 ? 0.f : 1.f;
            #pragma unroll
            for (int u = 0; u < 4; u++) {
                const f32x4 bv = *(const f32x4*)&bm2s[u * 16 + lq * 4];
                msgacc[u][mt] += bv;
                msgacc[u][mt] *= dm;
            }
        }
        #pragma unroll
        for (int u = 0; u < 4; u++) {
            f32x4 s = msgacc[u][0] + msgacc[u][1];
            #pragma unroll
            for (int r = 0; r < 4; r++) {
                float x = s[r];
                x += __shfl_xor(x, 1); x += __shfl_xor(x, 2);
                x += __shfl_xor(x, 4); x += __shfl_xor(x, 8);
                if (lm == 0) msump2[pass * 4 + wv][u * 16 + lq * 4 + r] = x;
            }
        }

        // ---------- phase 3: GEMM3 (Wt1^T @ MSG^T, relu) fused with Wt2 ----------
        f16x8 mb[2][2];  // [j-tile][k-half over m]
        #pragma unroll
        for (int jt = 0; jt < 2; jt++)
            #pragma unroll
            for (int kh = 0; kh < 2; kh++) {
                const int u0i = kh * 2, u1i = kh * 2 + 1;
                unsigned pa0 = pk2(msgacc[u0i][jt][0], msgacc[u0i][jt][1]);
                unsigned pa1 = pk2(msgacc[u1i][jt][0], msgacc[u1i][jt][1]);
                unsigned pb0 = pk2(msgacc[u0i][jt][2], msgacc[u0i][jt][3]);
                unsigned pb1 = pk2(msgacc[u1i][jt][2], msgacc[u1i][jt][3]);
                unsigned t0 = __shfl((int)pa0, s01);
                unsigned t1 = __shfl((int)pa1, s01);
                unsigned w0 = hi32 ? t1 : t0;
                t0 = __shfl((int)pb0, s01);
                t1 = __shfl((int)pb1, s01);
                unsigned w1 = hi32 ? t1 : t0;
                t0 = __shfl((int)pa0, s01 + 16);
                t1 = __shfl((int)pa1, s01 + 16);
                unsigned w2 = hi32 ? t1 : t0;
                t0 = __shfl((int)pb0, s01 + 16);
                t1 = __shfl((int)pb1, s01 + 16);
                unsigned w3 = hi32 ? t1 : t0;
                mb[jt][kh] = __builtin_bit_cast(f16x8, (u32x4){w0, w1, w2, w3});
            }

        float d00=0.f,d01=0.f,d02=0.f, d10=0.f,d11=0.f,d12=0.f;
        #pragma unroll 2
        for (int ht = 0; ht < 16; ht++) {
            const int hc = ht * 16 + lm;
            const f16x8 wa0 = *(const f16x8*)&W1Hg[hc * 64 + lq * 8];
            const f16x8 wa1 = *(const f16x8*)&W1Hg[hc * 64 + 32 + lq * 8];
            const f32x4 bt  = *(const f32x4*)&bt1s[ht * 16 + lq * 4];
            const f32x4 w20 = *(const f32x4*)&wt2sT[ht * 16 + lq * 4];
            const f32x4 w21 = *(const f32x4*)&wt2sT[256 + ht * 16 + lq * 4];
            const f32x4 w22 = *(const f32x4*)&wt2sT[512 + ht * 16 + lq * 4];
            {
                f32x4 acc = {0.f,0.f,0.f,0.f};
                acc = MFMA16(wa0, mb[0][0], acc);
                acc = MFMA16(wa1, mb[0][1], acc);
                #pragma unroll
                for (int r = 0; r < 4; r++) {
                    const float s = fmaxf(acc[r] + bt[r], 0.f);
                    d00 = fmaf(s, w20[r], d00);
                    d01 = fmaf(s, w21[r], d01);
                    d02 = fmaf(s, w22[r], d02);
                }
            }
            {
                f32x4 acc = {0.f,0.f,0.f,0.f};
                acc = MFMA16(wa0, mb[1][0], acc);
                acc = MFMA16(wa1, mb[1][1], acc);
                #pragma unroll
                for (int r = 0; r < 4; r++) {
                    const float s = fmaxf(acc[r] + bt[r], 0.f);
                    d10 = fmaf(s, w20[r], d10);
                    d11 = fmaf(s, w21[r], d11);
                    d12 = fmaf(s, w22[r], d12);
                }
            }
        }
        {
            float v0 = d00, v1 = d01, v2 = d02;
            v0 += __shfl_xor(v0, 16); v0 += __shfl_xor(v0, 32);
            v1 += __shfl_xor(v1, 16); v1 += __shfl_xor(v1, 32);
            v2 += __shfl_xor(v2, 16); v2 += __shfl_xor(v2, 32);
            if (lane < 16) {
                DXB[(jbase + lm) * 3 + 0] = v0;
                DXB[(jbase + lm) * 3 + 1] = v1;
                DXB[(jbase + lm) * 3 + 2] = v2;
            }
            v0 = d10; v1 = d11; v2 = d12;
            v0 += __shfl_xor(v0, 16); v0 += __shfl_xor(v0, 32);
            v1 += __shfl_xor(v1, 16); v1 += __shfl_xor(v1, 32);
            v2 += __shfl_xor(v2, 16); v2 += __shfl_xor(v2, 32);
            if (lane < 16) {
                DXB[(jbase + 16 + lm) * 3 + 0] = v0;
                DXB[(jbase + 16 + lm) * 3 + 1] = v1;
                DXB[(jbase + 16 + lm) * 3 + 2] = v2;
            }
        }
    }
    __syncthreads();  // barrier 2: msump2 + DXB complete (cross-wave)

    if (tid < 64) {
        float s = msump2[0][tid] + msump2[1][tid] + msump2[2][tid] + msump2[3][tid]
                + msump2[4][tid] + msump2[5][tid] + msump2[6][tid] + msump2[7][tid];
        MS_s[tid] = s; MSC_s[tid] = s * cfac;
    }

    // ---------------- phase 4: bt2 + mask + rotate + block reduce ----------------
    float qjw, qjx, qjy, qjz;
    {
        const float* qp = pep ? (pep_q + (b * N_ + j) * 4)
                              : (poc_q + (b * P_ + (j - N_)) * 4);
        const float4 q4 = *reinterpret_cast<const float4*>(qp);
        qjw = q4.x; qjx = q4.y; qjy = q4.z; qjz = q4.w;
    }
    const float maskf = (pep && j == i) ? 0.f : 1.f;
    float dx0 = (DXB[j * 3 + 0] + W.bt2[0]) * maskf;
    float dx1 = (DXB[j * 3 + 1] + W.bt2[1]) * maskf;
    float dx2 = (DXB[j * 3 + 2] + W.bt2[2]) * maskf;
    float rx, ry, rz;
    qrot(qjw, qjx, qjy, qjz, dx0, dx1, dx2, rx, ry, rz);
    {
        float v = rx;
        v += __shfl_xor(v, 32); v += __shfl_xor(v, 16); v += __shfl_xor(v, 8);
        v += __shfl_xor(v, 4);  v += __shfl_xor(v, 2);  v += __shfl_xor(v, 1);
        if (lane == 0) rotp[wv][0] = v;
        v = ry;
        v += __shfl_xor(v, 32); v += __shfl_xor(v, 16); v += __shfl_xor(v, 8);
        v += __shfl_xor(v, 4);  v += __shfl_xor(v, 2);  v += __shfl_xor(v, 1);
        if (lane == 0) rotp[wv][1] = v;
        v = rz;
        v += __shfl_xor(v, 32); v += __shfl_xor(v, 16); v += __shfl_xor(v, 8);
        v += __shfl_xor(v, 4);  v += __shfl_xor(v, 2);  v += __shfl_xor(v, 1);
        if (lane == 0) rotp[wv][2] = v;
    }
    __syncthreads();  // barrier 3: rotp cross-wave; POOL now dead -> tail reuses

    // ================== fused k_node tail ==================
    float* const FB = (float*)POOL;    // E/G dead after pass loop
    float* const HIS  = FB;            // [64]
    float* const TORs = FB + 64;       // [14]
    float* const HB   = FB + 128;      // [256] f-hidden
    float* const HB2  = FB + 384;      // [256] q-hidden
    float* const HB3  = FB + 640;      // [256] o-hidden

    if (tid >= 64 && tid < 67) {
        int k = tid - 64;
        ROT_s[k] = rotp[0][k] + rotp[1][k] + rotp[2][k] + rotp[3][k];
    }
    if (tid < 64) HIS[tid] = pep_h[(size_t)node * 64 + tid];
    if (tid >= 96 && tid < 110) TORs[tid - 96] = pep_t[(size_t)node * 14 + (tid - 96)];
    __syncthreads();  // barrier 4: HIS/TORs/ROT_s/MS_s visible

    // f1: HB = relu([HIS|MS] @ Wf1 + bf1)
    {
        float acc = W.bf1[tid];
        #pragma unroll 16
        for (int k = 0; k < 64; k++) acc = fmaf(HIS[k], W.Wf1[k * 256 + tid], acc);
        #pragma unroll 16
        for (int k = 0; k < 64; k++) acc = fmaf(MS_s[k], W.Wf1[(64 + k) * 256 + tid], acc);
        HB[tid] = fmaxf(acc, 0.f);
    }
    __syncthreads();  // barrier 5
    // f2 partials (wave wv covers c-range [wv*64, wv*64+64)), + q1, o1
    {
        float p = 0.f;
        #pragma unroll 16
        for (int c = 0; c < 64; c++)
            p = fmaf(HB[wv * 64 + c], W.Wf2[(wv * 64 + c) * 64 + lane], p);
        msump2[wv][lane] = p;  // msump2 rows 0..3 dead since MS_s -> reuse
    }
    {
        float acc = W.bq1[tid];
        #pragma unroll 16
        for (int k = 0; k < 64; k++) acc = fmaf(MSC_s[k], W.Wq1[k * 256 + tid], acc);
        HB2[tid] = fmaxf(acc, 0.f);
    }
    {
        float acc = W.bo1[tid];
        #pragma unroll 16
        for (int k = 0; k < 64; k++) acc = fmaf(MSC_s[k], W.Wo1[k * 256 + tid], acc);
        #pragma unroll
        for (int k = 0; k < 14; k++) acc = fmaf(TORs[k], W.Wo1[(64 + k) * 256 + tid], acc);
        HB3[tid] = fmaxf(acc, 0.f);
    }
    __syncthreads();  // barrier 6
    if (tid < 64) {
        float o = W.bf2[tid] + msump2[0][tid] + msump2[1][tid] + msump2[2][tid] + msump2[3][tid];
        out[OUT_O + (size_t)node * 64 + tid] = o;
    }
    // q2: wave wv computes dq[wv] (4 outputs, shfl-64 reduce)
    {
        float p = 0.f;
        #pragma unroll
        for (int t4 = 0; t4 < 4; t4++) {
            int c = t4 * 64 + lane;
            p = fmaf(HB2[c], W.Wq2[c * 4 + wv], p);
        }
        p += __shfl_xor(p, 32); p += __shfl_xor(p, 16); p += __shfl_xor(p, 8);
        p += __shfl_xor(p, 4);  p += __shfl_xor(p, 2);  p += __shfl_xor(p, 1);
        if (lane == 0) DQ_s[wv] = p + W.bq2[wv];
    }
    // o2: group g = tid>>4 (14 used of 16), 16 threads/group, shfl-16 reduce
    {
        const int g = tid >> 4, l16 = tid & 15;
        if (g < 14) {
            float p = 0.f;
            #pragma unroll
            for (int t16 = 0; t16 < 16; t16++) {
                int c = t16 * 16 + l16;
                p = fmaf(HB3[c], W.Wo2[c * 14 + g], p);
            }
            p += __shfl_xor(p, 8); p += __shfl_xor(p, 4);
            p += __shfl_xor(p, 2); p += __shfl_xor(p, 1);
            if (l16 == 0) DT_s[g] = p + W.bo2[g];
        }
    }
    __syncthreads();  // barrier 7: DQ_s/DT_s visible

    if (tid == 0) {
        float w_ = DQ_s[0], x_ = DQ_s[1], y_ = DQ_s[2], z_ = DQ_s[3];
        float n = fmaxf(sqrtf(w_ * w_ + x_ * x_ + y_ * y_ + z_ * z_), 1e-12f);
        w_ /= n; x_ /= n; y_ /= n; z_ /= n;
        const float4 qi4 = *reinterpret_cast<const float4*>(pep_q + (size_t)node * 4);
        float aw = qi4.x, ax = qi4.y, ay = qi4.z, az = qi4.w;
        float uw = aw * w_ - ax * x_ - ay * y_ - az * z_;
        float ux = aw * x_ + ax * w_ + ay * z_ - az * y_;
        float uy = aw * y_ - ax * z_ + ay * w_ + az * x_;
        float uz = aw * z_ + ax * y_ - ay * x_ + az * w_;
        float n2 = fmaxf(sqrtf(uw * uw + ux * ux + uy * uy + uz * uz), 1e-12f);
        out[OUT_UPDQ + (size_t)node * 4 + 0] = uw / n2;
        out[OUT_UPDQ + (size_t)node * 4 + 1] = ux / n2;
        out[OUT_UPDQ + (size_t)node * 4 + 2] = uy / n2;
        out[OUT_UPDQ + (size_t)node * 4 + 3] = uz / n2;
    }
    if (tid >= 32 && tid < 35) {
        int k = tid - 32;
        out[OUT_UPDX + (size_t)node * 3 + k] =
            pep_x[(size_t)node * 3 + k] + ROT_s[k] * cfac;
    }
    if (tid >= 48 && tid < 55) {
        int t = tid - 48;
        float s2 = DT_s[2 * t], c2 = DT_s[2 * t + 1];
        float n = fmaxf(sqrtf(s2 * s2 + c2 * c2), 1e-12f);
        s2 /= n; c2 /= n;
        float s1 = TORs[2 * t], c1 = TORs[2 * t + 1];
        out[OUT_UPDT + (size_t)node * 14 + 2 * t]     = s1 * c2 + c1 * s2;
        out[OUT_UPDT + (size_t)node * 14 + 2 * t + 1] = c1 * c2 - s1 * s2;
    }
}

extern "C" void kernel_launch(void* const* d_in, const int* in_sizes, int n_in,
                              void* d_out, int out_size, void* d_ws, size_t ws_size,
                              hipStream_t stream) {
    (void)in_sizes; (void)n_in; (void)out_size; (void)ws_size;
    const float* pep_q = (const float*)d_in[0];
    const float* pep_x = (const float*)d_in[1];
    const float* pep_t = (const float*)d_in[2];
    const float* pep_h = (const float*)d_in[3];
    const float* ef    = (const float*)d_in[4];
    const float* poc_h = (const float*)d_in[5];
    const float* poc_q = (const float*)d_in[6];
    const float* poc_x = (const float*)d_in[7];
    float* ws = (float*)d_ws;
    float* out = (float*)d_out;

    Wts W;
    W.Wm1 = (const float*)d_in[8];  W.bm1 = (const float*)d_in[9];
    W.Wm2 = (const float*)d_in[10]; W.bm2 = (const float*)d_in[11];
    W.Wf1 = (const float*)d_in[12]; W.bf1 = (const float*)d_in[13];
    W.Wf2 = (const float*)d_in[14]; W.bf2 = (const float*)d_in[15];
    W.Wt1 = (const float*)d_in[16]; W.bt1 = (const float*)d_in[17];
    W.Wt2 = (const float*)d_in[18]; W.bt2 = (const float*)d_in[19];
    W.Wq1 = (const float*)d_in[20]; W.bq1 = (const float*)d_in[21];
    W.Wq2 = (const float*)d_in[22]; W.bq2 = (const float*)d_in[23];
    W.Wo1 = (const float*)d_in[24]; W.bo1 = (const float*)d_in[25];
    W.Wo2 = (const float*)d_in[26]; W.bo2 = (const float*)d_in[27];

    k_prep<<<320, 256, 0, stream>>>(W.Wm1, W.Wm2, W.Wt1, ws);
    k_dots<<<dim3(4, 16), 256, 0, stream>>>(pep_h, poc_h, ws);
    k_edge<<<1024, 256, 0, stream>>>(pep_q, pep_x, pep_t, pep_h, ef,
                                     poc_q, poc_x, W, ws, out);
}

// Round 5
// 225.441 us; speedup vs baseline: 1.1376x; 1.1376x over previous
//
#include <hip/hip_runtime.h>

// EGNNLayer — MI355X (gfx950)
// B=16 N=64 P=192 NP=256 H=64 E=32 M=64 O=64 T=256
// dtypes: fp32 in/out. Masks all-True -> diag-only mask, n_msg=255.
//
// R20: revert R19 (j-split regressed: occupancy fell to 24%, mt 4->2 halved
//   ILP; allocator ignored the 116-reg budget). Base = R18 (112us, proven).
//   One change: explicit cross-chunk double-buffer of the GEMM1 weight
//   frags (g1e/g1g) — issue chunk ch+1's 4 global loads at top of chunk ch,
//   consume next iteration. Hides ~200-400cyc L2 latency under a full chunk
//   of compute (unroll-1 loop prevents the compiler doing this itself).
//   +16 arch VGPR -> ~96+64acc = 160 <= 170: 3 waves/SIMD tier preserved.

typedef _Float16 f16;
typedef f16 f16x8 __attribute__((ext_vector_type(8)));
typedef f16 f16x4 __attribute__((ext_vector_type(4)));
typedef float f32x4 __attribute__((ext_vector_type(4)));
typedef unsigned u32x4 __attribute__((ext_vector_type(4)));
#define MFMA16(a, b, c) __builtin_amdgcn_mfma_f32_16x16x32_f16(a, b, c, 0, 0, 0)

#define B_ 16
#define N_ 64
#define P_ 192
#define NP_ 256
#define H_ 64
#define T_ 256

// ---- ws layout (float offsets) ----
#define OFF_HIA    0         // (B*N, 256) fp32
#define OFF_HJB    262144    // (B, 256j, 256c) fp32  (transposed [j][c])
#define OFF_B1T    1379328   // f16 [256c][64k]
#define OFF_W2T    1387520   // f16 [64m][256c] = Wm2^T
#define OFF_WT1H   1395712   // f16 [256c][64m] = Wt1^T
#define OFF_W1AT   1403904   // f16 [256c][64k] = Wm1 rows 0..63 ^T
#define OFF_W1BT   1412096   // f16 [256c][64k] = Wm1 rows 64..127 ^T

// output layout (flat fp32)
#define OUT_UPDQ 0
#define OUT_UPDX 4096
#define OUT_UPDT 7168
#define OUT_O    21504

__device__ __forceinline__ void qrot(float qw, float qx, float qy, float qz,
                                     float vx, float vy, float vz,
                                     float& ox, float& oy, float& oz) {
    float tx = 2.f * (qy * vz - qz * vy);
    float ty = 2.f * (qz * vx - qx * vz);
    float tz = 2.f * (qx * vy - qy * vx);
    ox = vx + qw * tx + (qy * tz - qz * ty);
    oy = vy + qw * ty + (qz * tx - qx * tz);
    oz = vz + qw * tz + (qx * ty - qy * tx);
}

__device__ __forceinline__ unsigned pk2(float a, float b) {
    return __builtin_bit_cast(unsigned, __builtin_amdgcn_cvt_pkrtz(a, b));
}

struct Wts {
    const float *Wm1,*bm1,*Wm2,*bm2,*Wf1,*bf1,*Wf2,*bf2,*Wt1,*bt1,*Wt2,*bt2,
                *Wq1,*bq1,*Wq2,*bq2,*Wo1,*bo1,*Wo2,*bo2;
};

// grid 320 x 256: build B1T, W2T, WT1H, W1AT, W1BT (f16) in ws
__global__ __launch_bounds__(256) void k_prep(const float* __restrict__ Wm1,
                                              const float* __restrict__ Wm2,
                                              const float* __restrict__ Wt1,
                                              float* __restrict__ ws) {
    int t = blockIdx.x * 256 + threadIdx.x;  // < 81920
    if (t < 16384) {
        f16* B1T = (f16*)(ws + OFF_B1T);
        int c = t >> 6, k = t & 63;
        float v = 0.f;
        if (k < 32) v = Wm1[(128 + k) * 256 + c];
        else if (k < 41) v = Wm1[(160 + (k - 32)) * 256 + c];
        B1T[t] = (f16)v;
    } else if (t < 32768) {
        f16* W2T = (f16*)(ws + OFF_W2T);
        int u = t - 16384;
        int m = u >> 8, c = u & 255;
        W2T[u] = (f16)Wm2[c * 64 + m];
    } else if (t < 49152) {
        f16* W1H = (f16*)(ws + OFF_WT1H);
        int u = t - 32768;
        int c = u >> 6, m = u & 63;
        W1H[u] = (f16)Wt1[m * 256 + c];
    } else if (t < 65536) {
        f16* W1A = (f16*)(ws + OFF_W1AT);
        int u = t - 49152;
        int c = u >> 6, k = u & 63;
        W1A[u] = (f16)Wm1[k * 256 + c];
    } else {
        f16* W1B = (f16*)(ws + OFF_W1BT);
        int u = t - 65536;
        int c = u >> 6, k = u & 63;
        W1B[u] = (f16)Wm1[(64 + k) * 256 + c];
    }
}

// grid (4 ct, 16 b) x 256 — MFMA h-dots.  HJB stored transposed [j][c].
__global__ __launch_bounds__(256) void k_dots(const float* __restrict__ pep_h,
                                              const float* __restrict__ poc_h,
                                              float* __restrict__ ws) {
    const int ct = blockIdx.x;
    const int b = blockIdx.y;
    const int tid = threadIdx.x;
    const int lane = tid & 63;
    const int wv = tid >> 6;
    const int lm = lane & 15;
    const int lq = lane >> 4;

    __shared__ __align__(16) f16 hL[256 * 64];

    {
        const float4* p4 = (const float4*)(pep_h + (size_t)b * 4096);
        #pragma unroll
        for (int it = 0; it < 4; it++) {
            int idx = it * 256 + tid;
            float4 v = p4[idx];
            f16x4 h = {(f16)v.x, (f16)v.y, (f16)v.z, (f16)v.w};
            *(f16x4*)&hL[idx * 4] = h;
        }
        const float4* q4 = (const float4*)(poc_h + (size_t)b * 12288);
        #pragma unroll
        for (int it = 0; it < 12; it++) {
            int idx = it * 256 + tid;
            float4 v = q4[idx];
            f16x4 h = {(f16)v.x, (f16)v.y, (f16)v.z, (f16)v.w};
            *(f16x4*)&hL[4096 + idx * 4] = h;
        }
    }
    __syncthreads();

    const f16* W1AT = (const f16*)(ws + OFF_W1AT);
    const f16* W1BT = (const f16*)(ws + OFF_W1BT);

    f32x4 acc[4][4];
    #pragma unroll
    for (int mt = 0; mt < 4; mt++)
        #pragma unroll
        for (int nt = 0; nt < 4; nt++) acc[mt][nt] = (f32x4){0.f, 0.f, 0.f, 0.f};

    f16x8 af[4][2], bf[4][2];
    #pragma unroll
    for (int mt = 0; mt < 4; mt++) {
        const int c = ct * 64 + mt * 16 + lm;
        af[mt][0] = *(const f16x8*)&W1BT[c * 64 + lq * 8];
        af[mt][1] = *(const f16x8*)&W1BT[c * 64 + 32 + lq * 8];
    }
    #pragma unroll
    for (int nt = 0; nt < 4; nt++) {
        const int jj = wv * 64 + nt * 16 + lm;
        bf[nt][0] = *(const f16x8*)&hL[jj * 64 + lq * 8];
        bf[nt][1] = *(const f16x8*)&hL[jj * 64 + 32 + lq * 8];
    }
    #pragma unroll
    for (int mt = 0; mt < 4; mt++)
        #pragma unroll
        for (int nt = 0; nt < 4; nt++) {
            acc[mt][nt] = MFMA16(af[mt][0], bf[nt][0], acc[mt][nt]);
            acc[mt][nt] = MFMA16(af[mt][1], bf[nt][1], acc[mt][nt]);
        }
    // D[c][j] tile: row c = ct*64+mt*16+lq*4+r, col j = wv*64+nt*16+lm.
    // Store transposed [j][c] -> each lane writes a float4 along c.
    float* HJ = ws + OFF_HJB + (size_t)b * 65536;
    #pragma unroll
    for (int mt = 0; mt < 4; mt++)
        #pragma unroll
        for (int nt = 0; nt < 4; nt++)
            *(f32x4*)&HJ[(size_t)(wv * 64 + nt * 16 + lm) * 256 +
                         ct * 64 + mt * 16 + lq * 4] = acc[mt][nt];

    f32x4 ha[4];
    #pragma unroll
    for (int nt = 0; nt < 4; nt++) ha[nt] = (f32x4){0.f, 0.f, 0.f, 0.f};
    f16x8 a0 = *(const f16x8*)&hL[(wv * 16 + lm) * 64 + lq * 8];
    f16x8 a1 = *(const f16x8*)&hL[(wv * 16 + lm) * 64 + 32 + lq * 8];
    #pragma unroll
    for (int nt = 0; nt < 4; nt++) {
        const int c = ct * 64 + nt * 16 + lm;
        f16x8 b0 = *(const f16x8*)&W1AT[c * 64 + lq * 8];
        f16x8 b1 = *(const f16x8*)&W1AT[c * 64 + 32 + lq * 8];
        ha[nt] = MFMA16(a0, b0, ha[nt]);
        ha[nt] = MFMA16(a1, b1, ha[nt]);
    }
    #pragma unroll
    for (int nt = 0; nt < 4; nt++)
        #pragma unroll
        for (int r = 0; r < 4; r++)
            ws[OFF_HIA + (size_t)(b * 64 + wv * 16 + lq * 4 + r) * 256 +
               ct * 64 + nt * 16 + lm] = ha[nt][r];
}

// grid 1024 x 256.  XCD swizzle: b = blk&15, i = blk>>4.
// LDS 38.5 KB; launch_bounds(256,2): honest allocation (R15/R18-proven).
__global__ __launch_bounds__(256, 2) void k_edge(const float* __restrict__ pep_q,
                                                 const float* __restrict__ pep_x,
                                                 const float* __restrict__ pep_t,
                                                 const float* __restrict__ pep_h,
                                                 const float* __restrict__ ef,
                                                 const float* __restrict__ poc_q,
                                                 const float* __restrict__ poc_x,
                                                 Wts W, float* __restrict__ ws,
                                                 float* __restrict__ out) {
    const int b = blockIdx.x & 15;
    const int i = blockIdx.x >> 4;
    const int node = b * 64 + i;
    const int tid = threadIdx.x;
    const int j = tid;
    const int lane = tid & 63;
    const int wv = tid >> 6;
    const int lm = lane & 15;
    const int lq = lane >> 4;
    const int j0w = wv * 64;
    const float cfac = 1.f / 255.f;  // n_msg = 63 pep + 192 pocket

    // A1: [256 j][56 f16] (stride 112B = 28 dwords -> 2-way banks). Rows
    // 0..47 valid (edge 32 | geo 16), 48..55 pad (never multiplied: B1T rows
    // 48..63 are zero AND lq>=2 B-frag is zf). Dead after phase 1; tail FB
    // overlays it.
    __shared__ __align__(16) f16 A1[256 * 56];     // 28672 B
    __shared__ float DXB[4][192];                  // per-wave [64 j][3], 3072 B
    __shared__ float base_s[256], bt1s[256], wt2sT[768];
    __shared__ float msump[4][64];
    __shared__ float rotp[4][3];
    __shared__ float MS_s[64], MSC_s[64], ROT_s[3], DQ_s[4], DT_s[14];

    // ---------------- phase 0: staging + per-j geometry ----------------
    base_s[tid] = ws[OFF_HIA + (size_t)node * T_ + tid] + W.bm1[tid];
    bt1s[tid] = W.bt1[tid];
    wt2sT[tid]       = W.Wt2[tid * 3 + 0];   // Wt2^T: [3][256]
    wt2sT[256 + tid] = W.Wt2[tid * 3 + 1];
    wt2sT[512 + tid] = W.Wt2[tid * 3 + 2];

    const bool pep = (j < N_);
    {
        const float4 qi4 = *reinterpret_cast<const float4*>(pep_q + (b * N_ + i) * 4);
        const float qiw = qi4.x, qix = qi4.y, qiy = qi4.z, qiz = qi4.w;
        const float* tip = pep_x + (b * N_ + i) * 3;
        const float tix = tip[0], tiy = tip[1], tiz = tip[2];

        float qjw, qjx, qjy, qjz, xjx, xjy, xjz;
        if (pep) {
            const float4 q4 = *reinterpret_cast<const float4*>(pep_q + (b * N_ + j) * 4);
            qjw = q4.x; qjx = q4.y; qjy = q4.z; qjz = q4.w;
            const float* xp = pep_x + (b * N_ + j) * 3;
            xjx = xp[0]; xjy = xp[1]; xjz = xp[2];
        } else {
            const float4 q4 = *reinterpret_cast<const float4*>(poc_q + (b * P_ + (j - N_)) * 4);
            qjw = q4.x; qjx = q4.y; qjy = q4.z; qjz = q4.w;
            const float* xp = poc_x + (b * P_ + (j - N_)) * 3;
            xjx = xp[0]; xjy = xp[1]; xjz = xp[2];
        }

        const float vw = qjw, vx = -qjx, vy = -qjy, vz = -qjz;
        float tnx, tny, tnz;
        qrot(vw, vx, vy, vz, xjx, xjy, xjz, tnx, tny, tnz);
        float lxx, lxy, lxz;
        qrot(vw, vx, vy, vz, tix, tiy, tiz, lxx, lxy, lxz);
        lxx -= tnx; lxy -= tny; lxz -= tnz;
        float lqw = vw * qiw - vx * qix - vy * qiy - vz * qiz;
        float lqx = vw * qix + vx * qiw + vy * qiz - vz * qiy;
        float lqy = vw * qiy - vx * qiz + vy * qiw + vz * qix;
        float lqz = vw * qiz + vx * qiy - vy * qix + vz * qiw;
        float ddx = tix - xjx, ddy = tiy - xjy, ddz = tiz - xjz;
        float d2 = ddx * ddx + ddy * ddy + ddz * ddz;
        float qd = fabsf(qiw * qjw + qix * qjx + qiy * qjy + qiz * qjz);

        f16* arow = &A1[j * 56];
        const f16x8 z = {(f16)0,(f16)0,(f16)0,(f16)0,(f16)0,(f16)0,(f16)0,(f16)0};
        if (pep) {
            const float4* ep = reinterpret_cast<const float4*>(
                ef + (size_t)(((b * N_ + i) * N_) + j) * 32);
            #pragma unroll
            for (int gr = 0; gr < 4; gr++) {
                float4 v0 = ep[gr * 2], v1 = ep[gr * 2 + 1];
                f16x8 h;
                h[0]=(f16)v0.x; h[1]=(f16)v0.y; h[2]=(f16)v0.z; h[3]=(f16)v0.w;
                h[4]=(f16)v1.x; h[5]=(f16)v1.y; h[6]=(f16)v1.z; h[7]=(f16)v1.w;
                *(f16x8*)(arow + gr * 8) = h;
            }
        } else {
            #pragma unroll
            for (int gr = 0; gr < 4; gr++) *(f16x8*)(arow + gr * 8) = z;
        }
        f16x8 hg;
        hg[0]=(f16)lxx; hg[1]=(f16)lxy; hg[2]=(f16)lxz; hg[3]=(f16)lqw;
        hg[4]=(f16)lqx; hg[5]=(f16)lqy; hg[6]=(f16)lqz; hg[7]=(f16)d2;
        *(f16x8*)(arow + 32) = hg;
        f16x8 h2 = z; h2[0] = (f16)qd;
        *(f16x8*)(arow + 40) = h2;
    }
    __syncthreads();  // barrier 1

    const f16* B1Tg = (const f16*)(ws + OFF_B1T);
    const f16* W2Tg = (const f16*)(ws + OFF_W2T);
    const float* hjbT = ws + OFF_HJB + (size_t)b * 65536;

    // msgacc[m-tile u][j-tile jt]: MSG^T tiles — lane holds
    // m = u*16 + lq*4 + r, j(local) = jt*16 + lm.
    f32x4 msgacc[4][4];
    #pragma unroll
    for (int u = 0; u < 4; u++)
        #pragma unroll
        for (int jt = 0; jt < 4; jt++) msgacc[u][jt] = (f32x4){0.f,0.f,0.f,0.f};

    const f16x8 zf = {(f16)0,(f16)0,(f16)0,(f16)0,(f16)0,(f16)0,(f16)0,(f16)0};
    const int s01 = lm + (lq & 1) * 32;   // transpose-shuffle source (sq base)
    const bool hi32 = (lane >= 32);       // dest k-tile select (lq>>1)

    // ------- phase 1: 8 chunks of 32 c; GEMM1 weight frags double-buffered -------
    f16x8 g1e0 = zf, g1e1 = zf;
    if (wv == 0) {  // edge half k=0..31: nonzero only for peptide rows
        g1e0 = *(const f16x8*)&B1Tg[(lm) * 64 + lq * 8];
        g1e1 = *(const f16x8*)&B1Tg[(16 + lm) * 64 + lq * 8];
    }
    f16x8 g1g0 = *(const f16x8*)&B1Tg[(lm) * 64 + 32 + lq * 8];
    f16x8 g1g1 = *(const f16x8*)&B1Tg[(16 + lm) * 64 + 32 + lq * 8];

    #pragma unroll 1
    for (int ch = 0; ch < 8; ch++) {
        const int c0 = ch * 32;
        // prefetch chunk ch+1's GEMM1 frags: issued here, consumed next iter
        f16x8 n_e0 = zf, n_e1 = zf, n_g0 = zf, n_g1 = zf;
        if (ch < 7) {
            const int c1 = c0 + 32;
            if (wv == 0) {
                n_e0 = *(const f16x8*)&B1Tg[(c1 + lm) * 64 + lq * 8];
                n_e1 = *(const f16x8*)&B1Tg[(c1 + 16 + lm) * 64 + lq * 8];
            }
            n_g0 = *(const f16x8*)&B1Tg[(c1 + lm) * 64 + 32 + lq * 8];
            n_g1 = *(const f16x8*)&B1Tg[(c1 + 16 + lm) * 64 + 32 + lq * 8];
        }
        // A-frags (rows = m) for GEMM2 (current chunk)
        f16x8 g2[4];
        #pragma unroll
        for (int u = 0; u < 4; u++)
            g2[u] = *(const f16x8*)&W2Tg[(u * 16 + lm) * 256 + c0 + lq * 8];

        #pragma unroll
        for (int mt = 0; mt < 4; mt++) {
            const int jr = j0w + mt * 16 + lm;
            f16x8 a1 = zf;
            if (lq < 2) a1 = *(const f16x8*)&A1[jr * 56 + 32 + lq * 8];
            f16x8 a0 = zf;
            if (wv == 0) a0 = *(const f16x8*)&A1[jr * 56 + lq * 8];

            unsigned p00, p01, p10, p11;  // packed relu(T1) tiles nt=0,1
            {
                f32x4 acc = {0.f,0.f,0.f,0.f};
                if (wv == 0) acc = MFMA16(g1e0, a0, acc);
                acc = MFMA16(g1g0, a1, acc);
                const f32x4 hv = *(const f32x4*)&hjbT[(size_t)jr * 256 + c0 + lq * 4];
                const f32x4 bb = *(const f32x4*)&base_s[c0 + lq * 4];
                float u0 = fmaxf(acc[0] + hv[0] + bb[0], 0.f);
                float u1 = fmaxf(acc[1] + hv[1] + bb[1], 0.f);
                float u2 = fmaxf(acc[2] + hv[2] + bb[2], 0.f);
                float u3 = fmaxf(acc[3] + hv[3] + bb[3], 0.f);
                p00 = pk2(u0, u1); p01 = pk2(u2, u3);
            }
            {
                f32x4 acc = {0.f,0.f,0.f,0.f};
                if (wv == 0) acc = MFMA16(g1e1, a0, acc);
                acc = MFMA16(g1g1, a1, acc);
                const f32x4 hv = *(const f32x4*)&hjbT[(size_t)jr * 256 + c0 + 16 + lq * 4];
                const f32x4 bb = *(const f32x4*)&base_s[c0 + 16 + lq * 4];
                float u0 = fmaxf(acc[0] + hv[0] + bb[0], 0.f);
                float u1 = fmaxf(acc[1] + hv[1] + bb[1], 0.f);
                float u2 = fmaxf(acc[2] + hv[2] + bb[2], 0.f);
                float u3 = fmaxf(acc[3] + hv[3] + bb[3], 0.f);
                p10 = pk2(u0, u1); p11 = pk2(u2, u3);
            }
            // transpose: D[c][j] tiles -> B-frag [k=c][col=j] for GEMM2
            unsigned w0, w1, w2, w3;
            {
                unsigned t0 = __shfl((int)p00, s01);
                unsigned t1 = __shfl((int)p10, s01);
                w0 = hi32 ? t1 : t0;
                t0 = __shfl((int)p01, s01);
                t1 = __shfl((int)p11, s01);
                w1 = hi32 ? t1 : t0;
                t0 = __shfl((int)p00, s01 + 16);
                t1 = __shfl((int)p10, s01 + 16);
                w2 = hi32 ? t1 : t0;
                t0 = __shfl((int)p01, s01 + 16);
                t1 = __shfl((int)p11, s01 + 16);
                w3 = hi32 ? t1 : t0;
            }
            const f16x8 bfr = __builtin_bit_cast(f16x8, (u32x4){w0, w1, w2, w3});
            #pragma unroll
            for (int u = 0; u < 4; u++)
                msgacc[u][mt] = MFMA16(g2[u], bfr, msgacc[u][mt]);
        }
        g1e0 = n_e0; g1e1 = n_e1; g1g0 = n_g0; g1g1 = n_g1;
    }

    // -------- phase 2: bias + diag mask + msg_sum (all in registers) --------
    {
        f32x4 bm2v[4];
        #pragma unroll
        for (int u = 0; u < 4; u++)
            bm2v[u] = *(const f32x4*)&W.bm2[u * 16 + lq * 4];
        const int jti = i >> 4;
        const float dzero = (wv == 0 && lm == (i & 15)) ? 0.f : 1.f;
        #pragma unroll
        for (int jt = 0; jt < 4; jt++) {
            const float dm = (jt == jti) ? dzero : 1.f;
            #pragma unroll
            for (int u = 0; u < 4; u++) {
                msgacc[u][jt] += bm2v[u];
                msgacc[u][jt] *= dm;
            }
        }
    }
    #pragma unroll
    for (int u = 0; u < 4; u++) {
        f32x4 s = msgacc[u][0] + msgacc[u][1] + msgacc[u][2] + msgacc[u][3];
        #pragma unroll
        for (int r = 0; r < 4; r++) {
            float x = s[r];
            x += __shfl_xor(x, 1); x += __shfl_xor(x, 2);
            x += __shfl_xor(x, 4); x += __shfl_xor(x, 8);
            if (lm == 0) msump[wv][u * 16 + lq * 4 + r] = x;
        }
    }
    __syncthreads();  // barrier 2
    if (tid < 64) {
        float s = msump[0][tid] + msump[1][tid] + msump[2][tid] + msump[3][tid];
        MS_s[tid] = s; MSC_s[tid] = s * cfac;
    }

    // ---------- phase 3: hidden^T = relu(Wt1^T @ MSG^T + bt1), fused Wt2 ----------
    // pack MSG to f16 and shfl-transpose into 8 persistent B-frags.
    // Built per-(jt,kh) directly from msgacc (no 32-word mpa/mpb staging).
    f16x8 mb[4][2];  // [j-tile][k-half over m]
    #pragma unroll
    for (int jt = 0; jt < 4; jt++)
        #pragma unroll
        for (int kh = 0; kh < 2; kh++) {
            const int u0i = kh * 2, u1i = kh * 2 + 1;
            unsigned pa0 = pk2(msgacc[u0i][jt][0], msgacc[u0i][jt][1]);
            unsigned pa1 = pk2(msgacc[u1i][jt][0], msgacc[u1i][jt][1]);
            unsigned pb0 = pk2(msgacc[u0i][jt][2], msgacc[u0i][jt][3]);
            unsigned pb1 = pk2(msgacc[u1i][jt][2], msgacc[u1i][jt][3]);
            unsigned t0 = __shfl((int)pa0, s01);
            unsigned t1 = __shfl((int)pa1, s01);
            unsigned w0 = hi32 ? t1 : t0;
            t0 = __shfl((int)pb0, s01);
            t1 = __shfl((int)pb1, s01);
            unsigned w1 = hi32 ? t1 : t0;
            t0 = __shfl((int)pa0, s01 + 16);
            t1 = __shfl((int)pa1, s01 + 16);
            unsigned w2 = hi32 ? t1 : t0;
            t0 = __shfl((int)pb0, s01 + 16);
            t1 = __shfl((int)pb1, s01 + 16);
            unsigned w3 = hi32 ? t1 : t0;
            mb[jt][kh] = __builtin_bit_cast(f16x8, (u32x4){w0, w1, w2, w3});
        }

    const f16* W1Hg = (const f16*)(ws + OFF_WT1H);
    float d0[4] = {0,0,0,0}, d1[4] = {0,0,0,0}, d2a[4] = {0,0,0,0};
    #pragma unroll 2
    for (int ht = 0; ht < 16; ht++) {
        const int hc = ht * 16 + lm;
        const f16x8 wa0 = *(const f16x8*)&W1Hg[hc * 64 + lq * 8];
        const f16x8 wa1 = *(const f16x8*)&W1Hg[hc * 64 + 32 + lq * 8];
        const f32x4 bt  = *(const f32x4*)&bt1s[ht * 16 + lq * 4];
        const f32x4 w20 = *(const f32x4*)&wt2sT[ht * 16 + lq * 4];
        const f32x4 w21 = *(const f32x4*)&wt2sT[256 + ht * 16 + lq * 4];
        const f32x4 w22 = *(const f32x4*)&wt2sT[512 + ht * 16 + lq * 4];
        #pragma unroll
        for (int jt = 0; jt < 4; jt++) {
            f32x4 acc = {0.f,0.f,0.f,0.f};
            acc = MFMA16(wa0, mb[jt][0], acc);
            acc = MFMA16(wa1, mb[jt][1], acc);
            #pragma unroll
            for (int r = 0; r < 4; r++) {
                const float s = fmaxf(acc[r] + bt[r], 0.f);
                d0[jt]  = fmaf(s, w20[r], d0[jt]);
                d1[jt]  = fmaf(s, w21[r], d1[jt]);
                d2a[jt] = fmaf(s, w22[r], d2a[jt]);
            }
        }
    }
    float* const DXw = &DXB[wv][0];
    #pragma unroll
    for (int jt = 0; jt < 4; jt++) {
        float v0 = d0[jt], v1 = d1[jt], v2 = d2a[jt];
        v0 += __shfl_xor(v0, 16); v0 += __shfl_xor(v0, 32);
        v1 += __shfl_xor(v1, 16); v1 += __shfl_xor(v1, 32);
        v2 += __shfl_xor(v2, 16); v2 += __shfl_xor(v2, 32);
        if (lane < 16) {
            DXw[(jt * 16 + lm) * 3 + 0] = v0;
            DXw[(jt * 16 + lm) * 3 + 1] = v1;
            DXw[(jt * 16 + lm) * 3 + 2] = v2;
        }
    }
    __builtin_amdgcn_wave_barrier();  // same-wave DS RAW ordering (DXw)

    // ---------------- phase 4: bt2 + mask + rotate + block reduce ----------------
    float qjw, qjx, qjy, qjz;
    {
        const float* qp = pep ? (pep_q + (b * N_ + j) * 4)
                              : (poc_q + (b * P_ + (j - N_)) * 4);
        const float4 q4 = *reinterpret_cast<const float4*>(qp);
        qjw = q4.x; qjx = q4.y; qjy = q4.z; qjz = q4.w;
    }
    const float maskf = (pep && j == i) ? 0.f : 1.f;
    float dx0 = (DXw[lane * 3 + 0] + W.bt2[0]) * maskf;
    float dx1 = (DXw[lane * 3 + 1] + W.bt2[1]) * maskf;
    float dx2 = (DXw[lane * 3 + 2] + W.bt2[2]) * maskf;
    float rx, ry, rz;
    qrot(qjw, qjx, qjy, qjz, dx0, dx1, dx2, rx, ry, rz);
    {
        float v = rx;
        v += __shfl_xor(v, 32); v += __shfl_xor(v, 16); v += __shfl_xor(v, 8);
        v += __shfl_xor(v, 4);  v += __shfl_xor(v, 2);  v += __shfl_xor(v, 1);
        if (lane == 0) rotp[wv][0] = v;
        v = ry;
        v += __shfl_xor(v, 32); v += __shfl_xor(v, 16); v += __shfl_xor(v, 8);
        v += __shfl_xor(v, 4);  v += __shfl_xor(v, 2);  v += __shfl_xor(v, 1);
        if (lane == 0) rotp[wv][1] = v;
        v = rz;
        v += __shfl_xor(v, 32); v += __shfl_xor(v, 16); v += __shfl_xor(v, 8);
        v += __shfl_xor(v, 4);  v += __shfl_xor(v, 2);  v += __shfl_xor(v, 1);
        if (lane == 0) rotp[wv][2] = v;
    }
    __syncthreads();  // barrier 3: rotp cross-wave; A1 now dead -> tail reuses

    // ================== fused k_node tail ==================
    float* const FB = (float*)A1;      // A1 dead after phase 1
    float* const HIS  = FB;            // [64]
    float* const TORs = FB + 64;       // [14]
    float* const HB   = FB + 128;      // [256] f-hidden
    float* const HB2  = FB + 384;      // [256] q-hidden
    float* const HB3  = FB + 640;      // [256] o-hidden

    if (tid >= 64 && tid < 67) {
        int k = tid - 64;
        ROT_s[k] = rotp[0][k] + rotp[1][k] + rotp[2][k] + rotp[3][k];
    }
    if (tid < 64) HIS[tid] = pep_h[(size_t)node * 64 + tid];
    if (tid >= 96 && tid < 110) TORs[tid - 96] = pep_t[(size_t)node * 14 + (tid - 96)];
    __syncthreads();  // barrier 4: HIS/TORs/ROT_s/MS_s visible

    // f1: HB = relu([HIS|MS] @ Wf1 + bf1)
    {
        float acc = W.bf1[tid];
        #pragma unroll 16
        for (int k = 0; k < 64; k++) acc = fmaf(HIS[k], W.Wf1[k * 256 + tid], acc);
        #pragma unroll 16
        for (int k = 0; k < 64; k++) acc = fmaf(MS_s[k], W.Wf1[(64 + k) * 256 + tid], acc);
        HB[tid] = fmaxf(acc, 0.f);
    }
    __syncthreads();  // barrier 5
    // f2 partials (wave wv covers c-range [wv*64, wv*64+64)), + q1, o1
    {
        float p = 0.f;
        #pragma unroll 16
        for (int c = 0; c < 64; c++)
            p = fmaf(HB[wv * 64 + c], W.Wf2[(wv * 64 + c) * 64 + lane], p);
        msump[wv][lane] = p;  // msump dead since barrier 2 -> reuse as partials
    }
    {
        float acc = W.bq1[tid];
        #pragma unroll 16
        for (int k = 0; k < 64; k++) acc = fmaf(MSC_s[k], W.Wq1[k * 256 + tid], acc);
        HB2[tid] = fmaxf(acc, 0.f);
    }
    {
        float acc = W.bo1[tid];
        #pragma unroll 16
        for (int k = 0; k < 64; k++) acc = fmaf(MSC_s[k], W.Wo1[k * 256 + tid], acc);
        #pragma unroll
        for (int k = 0; k < 14; k++) acc = fmaf(TORs[k], W.Wo1[(64 + k) * 256 + tid], acc);
        HB3[tid] = fmaxf(acc, 0.f);
    }
    __syncthreads();  // barrier 6
    if (tid < 64) {
        float o = W.bf2[tid] + msump[0][tid] + msump[1][tid] + msump[2][tid] + msump[3][tid];
        out[OUT_O + (size_t)node * 64 + tid] = o;
    }
    // q2: wave wv computes dq[wv] (4 outputs, shfl-64 reduce)
    {
        float p = 0.f;
        #pragma unroll
        for (int t4 = 0; t4 < 4; t4++) {
            int c = t4 * 64 + lane;
            p = fmaf(HB2[c], W.Wq2[c * 4 + wv], p);
        }
        p += __shfl_xor(p, 32); p += __shfl_xor(p, 16); p += __shfl_xor(p, 8);
        p += __shfl_xor(p, 4);  p += __shfl_xor(p, 2);  p += __shfl_xor(p, 1);
        if (lane == 0) DQ_s[wv] = p + W.bq2[wv];
    }
    // o2: group g = tid>>4 (14 used of 16), 16 threads/group, shfl-16 reduce
    {
        const int g = tid >> 4, l16 = tid & 15;
        if (g < 14) {
            float p = 0.f;
            #pragma unroll
            for (int t16 = 0; t16 < 16; t16++) {
                int c = t16 * 16 + l16;
                p = fmaf(HB3[c], W.Wo2[c * 14 + g], p);
            }
            p += __shfl_xor(p, 8); p += __shfl_xor(p, 4);
            p += __shfl_xor(p, 2); p += __shfl_xor(p, 1);
            if (l16 == 0) DT_s[g] = p + W.bo2[g];
        }
    }
    __syncthreads();  // barrier 7: DQ_s/DT_s visible

    if (tid == 0) {
        float w_ = DQ_s[0], x_ = DQ_s[1], y_ = DQ_s[2], z_ = DQ_s[3];
        float n = fmaxf(sqrtf(w_ * w_ + x_ * x_ + y_ * y_ + z_ * z_), 1e-12f);
        w_ /= n; x_ /= n; y_ /= n; z_ /= n;
        const float4 qi4 = *reinterpret_cast<const float4*>(pep_q + (size_t)node * 4);
        float aw = qi4.x, ax = qi4.y, ay = qi4.z, az = qi4.w;
        float uw = aw * w_ - ax * x_ - ay * y_ - az * z_;
        float ux = aw * x_ + ax * w_ + ay * z_ - az * y_;
        float uy = aw * y_ - ax * z_ + ay * w_ + az * x_;
        float uz = aw * z_ + ax * y_ - ay * x_ + az * w_;
        float n2 = fmaxf(sqrtf(uw * uw + ux * ux + uy * uy + uz * uz), 1e-12f);
        out[OUT_UPDQ + (size_t)node * 4 + 0] = uw / n2;
        out[OUT_UPDQ + (size_t)node * 4 + 1] = ux / n2;
        out[OUT_UPDQ + (size_t)node * 4 + 2] = uy / n2;
        out[OUT_UPDQ + (size_t)node * 4 + 3] = uz / n2;
    }
    if (tid >= 32 && tid < 35) {
        int k = tid - 32;
        out[OUT_UPDX + (size_t)node * 3 + k] =
            pep_x[(size_t)node * 3 + k] + ROT_s[k] * cfac;
    }
    if (tid >= 48 && tid < 55) {
        int t = tid - 48;
        float s2 = DT_s[2 * t], c2 = DT_s[2 * t + 1];
        float n = fmaxf(sqrtf(s2 * s2 + c2 * c2), 1e-12f);
        s2 /= n; c2 /= n;
        float s1 = TORs[2 * t], c1 = TORs[2 * t + 1];
        out[OUT_UPDT + (size_t)node * 14 + 2 * t]     = s1 * c2 + c1 * s2;
        out[OUT_UPDT + (size_t)node * 14 + 2 * t + 1] = c1 * c2 - s1 * s2;
    }
}

extern "C" void kernel_launch(void* const* d_in, const int* in_sizes, int n_in,
                              void* d_out, int out_size, void* d_ws, size_t ws_size,
                              hipStream_t stream) {
    (void)in_sizes; (void)n_in; (void)out_size; (void)ws_size;
    const float* pep_q = (const float*)d_in[0];
    const float* pep_x = (const float*)d_in[1];
    const float* pep_t = (const float*)d_in[2];
    const float* pep_h = (const float*)d_in[3];
    const float* ef    = (const float*)d_in[4];
    const float* poc_h = (const float*)d_in[5];
    const float* poc_q = (const float*)d_in[6];
    const float* poc_x = (const float*)d_in[7];
    float* ws = (float*)d_ws;
    float* out = (float*)d_out;

    Wts W;
    W.Wm1 = (const float*)d_in[8];  W.bm1 = (const float*)d_in[9];
    W.Wm2 = (const float*)d_in[10]; W.bm2 = (const float*)d_in[11];
    W.Wf1 = (const float*)d_in[12]; W.bf1 = (const float*)d_in[13];
    W.Wf2 = (const float*)d_in[14]; W.bf2 = (const float*)d_in[15];
    W.Wt1 = (const float*)d_in[16]; W.bt1 = (const float*)d_in[17];
    W.Wt2 = (const float*)d_in[18]; W.bt2 = (const float*)d_in[19];
    W.Wq1 = (const float*)d_in[20]; W.bq1 = (const float*)d_in[21];
    W.Wq2 = (const float*)d_in[22]; W.bq2 = (const float*)d_in[23];
    W.Wo1 = (const float*)d_in[24]; W.bo1 = (const float*)d_in[25];
    W.Wo2 = (const float*)d_in[26]; W.bo2 = (const float*)d_in[27];

    k_prep<<<320, 256, 0, stream>>>(W.Wm1, W.Wm2, W.Wt1, ws);
    k_dots<<<dim3(4, 16), 256, 0, stream>>>(pep_h, poc_h, ws);
    k_edge<<<1024, 256, 0, stream>>>(pep_q, pep_x, pep_t, pep_h, ef,
                                     poc_q, poc_x, W, ws, out);
}